// Round 9
// baseline (208.222 us; speedup 1.0000x reference)
//
#include <hip/hip_runtime.h>
#include <hip/hip_bf16.h>

#define NN 100000
#define NE 1200000
#define NG 256
#define NB 256          // dst buckets
#define BSZ 391         // nodes per bucket (ceil(NN/NB))
#define NBK1 128        // ph0/ph1 blocks
#define ECH 9376        // edges per block (128*9376 >= NE)
#define MAXB 6144       // max edges per bucket (mean 4692)
#define NBND_BLK 391    // ceil(NN/256) for bounds
#define NPAD_BLK 6250   // NN*16/256

typedef __attribute__((ext_vector_type(8))) short bf16x8;
typedef __attribute__((ext_vector_type(4))) float f32x4;

// bf16 helpers (RNE)
__device__ __forceinline__ unsigned f2b(float f) {
    unsigned b = __float_as_uint(f);
    return (b + 0x7FFFu + ((b >> 16) & 1u)) >> 16;
}
__device__ __forceinline__ float b2f(unsigned short u) {
    return __uint_as_float((unsigned)u << 16);
}
__device__ __forceinline__ float4 b2f4(ushort4 u) {
    return make_float4(b2f(u.x), b2f(u.y), b2f(u.z), b2f(u.w));
}
// accumulate 8 bf16 channels (uint4) into float[8]
__device__ __forceinline__ void add_u4(float* a, uint4 v) {
    const unsigned* u = (const unsigned*)&v;
#pragma unroll
    for (int i = 0; i < 4; ++i) {
        a[2*i]   += __uint_as_float(u[i] << 16);
        a[2*i+1] += __uint_as_float(u[i] & 0xFFFF0000u);
    }
}

// ---------------------------------------------------------------------------
// Phase 0: per-block bucket histogram rows (no global atomics, no memset)
__global__ void ph0_hist(const int* __restrict__ dst, int* __restrict__ hrows) {
    __shared__ int h[NB];
    const int t = threadIdx.x;
    h[t] = 0;
    __syncthreads();
    const int e0 = blockIdx.x * ECH;
    const int cnt = min(ECH, NE - e0);
    for (int i = t; i < cnt; i += 256)
        atomicAdd(&h[dst[e0 + i] / BSZ], 1);
    __syncthreads();
    hrows[blockIdx.x * NB + t] = h[t];
}

// Phase 0b: column-scan hrows -> per-(block,bucket) chunk offsets + bbase
__global__ void ph_scan(const int* __restrict__ hrows, int* __restrict__ chunkoff,
                        int* __restrict__ bbase, int* __restrict__ row_off) {
    __shared__ int s[NB];
    const int t = threadIdx.x;
    int run = 0;
    for (int b = 0; b < NBK1; ++b) {
        int v = hrows[b * NB + t];
        chunkoff[b * NB + t] = run;
        run += v;
    }
    s[t] = run;
    __syncthreads();
    for (int off = 1; off < NB; off <<= 1) {
        int u = (t >= off) ? s[t - off] : 0;
        __syncthreads();
        s[t] += u;
        __syncthreads();
    }
    const int excl = s[t] - run;
    bbase[t] = excl;
    for (int b = 0; b < NBK1; ++b) chunkoff[b * NB + t] += excl;
    if (t == NB - 1) { bbase[NB] = NE; row_off[NN] = NE; }
}

// Phase 1: single-pass bucketize, LDS cursors only (no global atomics)
__global__ void ph1_bucketize(const int* __restrict__ src, const int* __restrict__ dst,
                              const int* __restrict__ chunkoff, unsigned* __restrict__ barray) {
    __shared__ int lbase[NB];
    __shared__ int lcur[NB];
    const int t = threadIdx.x;
    lbase[t] = chunkoff[blockIdx.x * NB + t];
    lcur[t] = 0;
    __syncthreads();
    const int e0 = blockIdx.x * ECH;
    const int cnt = min(ECH, NE - e0);
    for (int i = t; i < cnt; i += 256) {
        int d = dst[e0 + i], s = src[e0 + i];
        int b = d / BSZ;
        int pos = lbase[b] + atomicAdd(&lcur[b], 1);
        barray[pos] = ((unsigned)(d - b * BSZ) << 17) | (unsigned)s;
    }
}

// Phase 2: per-bucket CSR build, all global writes coalesced
__global__ void ph2_build(const unsigned* __restrict__ barray, const int* __restrict__ bbase,
                          int* __restrict__ row_off, float* __restrict__ dinv,
                          int* __restrict__ csr) {
    __shared__ unsigned estage[MAXB];
    __shared__ int lcsr[MAXB];
    __shared__ int s[512];
    __shared__ int cur[BSZ];
    const int t = threadIdx.x;
    const int b = blockIdx.x;
    const int ebase = bbase[b];
    const int cnt = bbase[b + 1] - ebase;
    const int nbase = b * BSZ;
    const int nnodes = min(BSZ, NN - nbase);
    s[t] = 0; s[t + 256] = 0;
    __syncthreads();
    for (int i = t; i < cnt; i += 256) {
        unsigned e = barray[ebase + i];
        estage[i] = e;
        atomicAdd(&s[e >> 17], 1);
    }
    __syncthreads();
    for (int off = 1; off < 512; off <<= 1) {
        int v1 = (t >= off) ? s[t - off] : 0;
        int v2 = s[t + 256 - off];
        __syncthreads();
        s[t] += v1; s[t + 256] += v2;
        __syncthreads();
    }
    for (int l = t; l < nnodes; l += 256) {
        int incl = s[l];
        int excl = l ? s[l - 1] : 0;
        row_off[nbase + l] = ebase + excl;
        dinv[nbase + l] = rsqrtf((float)(incl - excl) + 1.0f);
        cur[l] = excl;
    }
    __syncthreads();
    for (int i = t; i < cnt; i += 256) {
        unsigned e = estage[i];
        int pos = atomicAdd(&cur[e >> 17], 1);
        lcsr[pos] = (int)(e & 0x1FFFFu);
    }
    __syncthreads();
    for (int i = t; i < cnt; i += 256)
        csr[ebase + i] = lcsr[i];
}

// ---------------------------------------------------------------------------
// Combined prep: blocks [0,3) W-split, [3,394) pool bounds, [394,...) x pad
__global__ void k_prep(const float* __restrict__ W2, const float* __restrict__ W3,
                       const float* __restrict__ W4, unsigned short* __restrict__ wt,
                       const float* __restrict__ x, const float* __restrict__ dinv,
                       unsigned short* __restrict__ xs,
                       const int* __restrict__ batch, int* __restrict__ gstart) {
    const int blk = blockIdx.x;
    const int t = threadIdx.x;
    if (blk < 3) {
        // W -> transposed, hi/lo-split bf16: per layer [hi 64x64][lo 64x64]
        const float* W = (blk == 0) ? W2 : (blk == 1) ? W3 : W4;
        unsigned short* o = wt + blk * 8192;
        const int n = t >> 2;
        const int j0 = (t & 3) * 16;
#pragma unroll
        for (int j = 0; j < 16; ++j) {
            float wv = W[(j0 + j) * 64 + n];
            unsigned short h = (unsigned short)f2b(wv);
            o[n * 64 + j0 + j] = h;
            o[4096 + n * 64 + j0 + j] = (unsigned short)f2b(wv - b2f(h));
        }
    } else if (blk < 3 + NBND_BLK) {
        int i = (blk - 3) * 256 + t;
        if (i >= NN) return;
        int b = batch[i];
        if (i == 0) {
            for (int g = 0; g <= b; ++g) gstart[g] = 0;
        } else {
            int bp = batch[i - 1];
            for (int g = bp + 1; g <= b; ++g) gstart[g] = i;
        }
        if (i == NN - 1) {
            for (int g = b + 1; g <= NG; ++g) gstart[g] = NN;
        }
    } else {
        int i = (blk - 3 - NBND_BLK) * 256 + t;
        if (i < NN * 16) {
            int n = i >> 4, k = i & 15;
            float v = (k < 15) ? dinv[n] * x[n * 15 + k] : 0.f;
            xs[i] = (unsigned short)f2b(v);
        }
    }
}

// ---------------------------------------------------------------------------
// Layer 1: 16-d bf16 gather -> 16x64 matmul (VALU) -> bf16 out. 64 nodes/block.
__global__ void fused1(const unsigned short* __restrict__ xs, const int* __restrict__ row_off,
                       const int* __restrict__ csr, const float* __restrict__ dinv,
                       const float* __restrict__ W, const float* __restrict__ bias,
                       unsigned* __restrict__ out) {
    __shared__ float4 Wl[16][16];
    __shared__ float  al[64][20];
    const int t = threadIdx.x;
    if (t < 240) Wl[t >> 4][t & 15] = ((const float4*)W)[t];
    if (t < 16) Wl[15][t] = make_float4(0,0,0,0);
    const int nl = t >> 2, c4 = t & 3;
    const int node = blockIdx.x * 64 + nl;
    float4 acc = make_float4(0,0,0,0);
    float dv = 0.f;
    if (node < NN) {
        const ushort4* base = (const ushort4*)xs;
        acc = b2f4(base[(size_t)node * 4 + c4]);
        int p = row_off[node], e = row_off[node + 1];
        for (; p + 3 < e; p += 4) {
            int s0 = csr[p], s1 = csr[p+1], s2 = csr[p+2], s3 = csr[p+3];
            float4 a = b2f4(base[(size_t)s0 * 4 + c4]);
            float4 b = b2f4(base[(size_t)s1 * 4 + c4]);
            float4 c = b2f4(base[(size_t)s2 * 4 + c4]);
            float4 d = b2f4(base[(size_t)s3 * 4 + c4]);
            acc.x += (a.x + b.x) + (c.x + d.x);
            acc.y += (a.y + b.y) + (c.y + d.y);
            acc.z += (a.z + b.z) + (c.z + d.z);
            acc.w += (a.w + b.w) + (c.w + d.w);
        }
        for (; p < e; ++p) {
            float4 a = b2f4(base[(size_t)csr[p] * 4 + c4]);
            acc.x += a.x; acc.y += a.y; acc.z += a.z; acc.w += a.w;
        }
        dv = dinv[node];
        acc.x *= dv; acc.y *= dv; acc.z *= dv; acc.w *= dv;
    }
    ((float4*)&al[nl][0])[c4] = acc;
    __syncthreads();
    if (node >= NN) return;
    float4 o0 = ((const float4*)bias)[c4 * 4 + 0];
    float4 o1 = ((const float4*)bias)[c4 * 4 + 1];
    float4 o2 = ((const float4*)bias)[c4 * 4 + 2];
    float4 o3 = ((const float4*)bias)[c4 * 4 + 3];
#pragma unroll
    for (int k = 0; k < 16; ++k) {
        float a = al[nl][k];
        float4 w0 = Wl[k][c4 * 4 + 0];
        float4 w1 = Wl[k][c4 * 4 + 1];
        float4 w2 = Wl[k][c4 * 4 + 2];
        float4 w3 = Wl[k][c4 * 4 + 3];
        o0.x = fmaf(a, w0.x, o0.x); o0.y = fmaf(a, w0.y, o0.y); o0.z = fmaf(a, w0.z, o0.z); o0.w = fmaf(a, w0.w, o0.w);
        o1.x = fmaf(a, w1.x, o1.x); o1.y = fmaf(a, w1.y, o1.y); o1.z = fmaf(a, w1.z, o1.z); o1.w = fmaf(a, w1.w, o1.w);
        o2.x = fmaf(a, w2.x, o2.x); o2.y = fmaf(a, w2.y, o2.y); o2.z = fmaf(a, w2.z, o2.z); o2.w = fmaf(a, w2.w, o2.w);
        o3.x = fmaf(a, w3.x, o3.x); o3.y = fmaf(a, w3.y, o3.y); o3.z = fmaf(a, w3.z, o3.z); o3.w = fmaf(a, w3.w, o3.w);
    }
    float dv2 = dv;
    o0.x = fmaxf(o0.x, 0.f) * dv2; o0.y = fmaxf(o0.y, 0.f) * dv2; o0.z = fmaxf(o0.z, 0.f) * dv2; o0.w = fmaxf(o0.w, 0.f) * dv2;
    o1.x = fmaxf(o1.x, 0.f) * dv2; o1.y = fmaxf(o1.y, 0.f) * dv2; o1.z = fmaxf(o1.z, 0.f) * dv2; o1.w = fmaxf(o1.w, 0.f) * dv2;
    o2.x = fmaxf(o2.x, 0.f) * dv2; o2.y = fmaxf(o2.y, 0.f) * dv2; o2.z = fmaxf(o2.z, 0.f) * dv2; o2.w = fmaxf(o2.w, 0.f) * dv2;
    o3.x = fmaxf(o3.x, 0.f) * dv2; o3.y = fmaxf(o3.y, 0.f) * dv2; o3.z = fmaxf(o3.z, 0.f) * dv2; o3.w = fmaxf(o3.w, 0.f) * dv2;
    uint4 lo, hi;
    lo.x = f2b(o0.x) | (f2b(o0.y) << 16);
    lo.y = f2b(o0.z) | (f2b(o0.w) << 16);
    lo.z = f2b(o1.x) | (f2b(o1.y) << 16);
    lo.w = f2b(o1.z) | (f2b(o1.w) << 16);
    hi.x = f2b(o2.x) | (f2b(o2.y) << 16);
    hi.y = f2b(o2.z) | (f2b(o2.w) << 16);
    hi.z = f2b(o3.x) | (f2b(o3.y) << 16);
    hi.w = f2b(o3.z) | (f2b(o3.w) << 16);
    uint4* ob = (uint4*)out + (size_t)node * 8 + c4 * 2;
    ob[0] = lo; ob[1] = hi;
}

// ---------------------------------------------------------------------------
// Layers 2..4: bf16 gather (8 lanes x 16B/row, 2 sub-groups/node, unroll-8,
// shfl_xor combine) -> MFMA 16x16x32 hi/lo split. W fragments loaded straight
// from L2-hot global table (no B LDS staging -> 4.8 KB LDS, 8 blocks/CU).
template <bool LAST>
__global__ __launch_bounds__(256) void fused64(const unsigned short* __restrict__ g,
                        const int* __restrict__ row_off, const int* __restrict__ csr,
                        const float* __restrict__ dinv, const unsigned short* __restrict__ wt,
                        const float* __restrict__ bias, void* __restrict__ outv) {
    __shared__ alignas(16) unsigned short Ahi[16][72];
    __shared__ alignas(16) unsigned short Alo[16][72];
    __shared__ alignas(16) float dinv_l[16];
    const int t = threadIdx.x;

    // gather: node = t>>4; sub-group s8 = (t>>3)&1 takes half the edges;
    // lane q = t&7 covers channels q*8..q*8+7 (one uint4 = 16 B of the row).
    const int nl = t >> 4;
    const int s8 = (t >> 3) & 1;
    const int q  = t & 7;
    const int node = blockIdx.x * 16 + nl;
    float acc[8] = {0,0,0,0,0,0,0,0};
    const float dv = dinv[node];
    {
        const uint4* fbase = (const uint4*)g;        // row = 8 x uint4 (128 B)
        const int r0 = row_off[node], r1 = row_off[node + 1];
        const int half = (r1 - r0 + 1) >> 1;
        int p = r0 + s8 * half;
        const int e = s8 ? r1 : (r0 + half);
        if (s8 == 0) add_u4(acc, fbase[(size_t)node * 8 + q]);   // self-loop
        int i0 = csr[p],   i1 = csr[p+1], i2 = csr[p+2], i3 = csr[p+3];
        int i4 = csr[p+4], i5 = csr[p+5], i6 = csr[p+6], i7 = csr[p+7];
        while (p < e) {
            const int rem = e - p;
            uint4 v0, v1, v2, v3, v4, v5, v6, v7;
            v0 = fbase[(size_t)i0 * 8 + q];
            if (rem > 1) v1 = fbase[(size_t)i1 * 8 + q];
            if (rem > 2) v2 = fbase[(size_t)i2 * 8 + q];
            if (rem > 3) v3 = fbase[(size_t)i3 * 8 + q];
            if (rem > 4) v4 = fbase[(size_t)i4 * 8 + q];
            if (rem > 5) v5 = fbase[(size_t)i5 * 8 + q];
            if (rem > 6) v6 = fbase[(size_t)i6 * 8 + q];
            if (rem > 7) v7 = fbase[(size_t)i7 * 8 + q];
            p += 8;
            i0 = csr[p];   i1 = csr[p+1]; i2 = csr[p+2]; i3 = csr[p+3];
            i4 = csr[p+4]; i5 = csr[p+5]; i6 = csr[p+6]; i7 = csr[p+7];
            add_u4(acc, v0);
            if (rem > 1) add_u4(acc, v1);
            if (rem > 2) add_u4(acc, v2);
            if (rem > 3) add_u4(acc, v3);
            if (rem > 4) add_u4(acc, v4);
            if (rem > 5) add_u4(acc, v5);
            if (rem > 6) add_u4(acc, v6);
            if (rem > 7) add_u4(acc, v7);
        }
    }
    // combine the two sub-groups in-register (lanes differ in bit 3)
#pragma unroll
    for (int i = 0; i < 8; ++i) acc[i] += __shfl_xor(acc[i], 8, 64);
    if (s8 == 0) {
        uint4 uh, ul;
        unsigned* uhp = (unsigned*)&uh;
        unsigned* ulp = (unsigned*)&ul;
#pragma unroll
        for (int i = 0; i < 4; ++i) {
            float va = acc[2*i] * dv;
            float vb = acc[2*i+1] * dv;
            unsigned ha = f2b(va), hb = f2b(vb);
            unsigned la = f2b(va - b2f((unsigned short)ha));
            unsigned lb = f2b(vb - b2f((unsigned short)hb));
            uhp[i] = ha | (hb << 16);
            ulp[i] = la | (lb << 16);
        }
        *(uint4*)&Ahi[nl][q * 8] = uh;
        *(uint4*)&Alo[nl][q * 8] = ul;
        if (q == 0) dinv_l[nl] = dv;
    }
    // W fragments from global (same 16 KB table for all blocks -> L2-hot)
    const int wid = t >> 6;
    const int l = t & 63;
    const int rr = l & 15;
    const int kb = l >> 4;
    const unsigned short* wrow = wt + (wid * 16 + rr) * 64;
    bf16x8 bh0 = *(const bf16x8*)(wrow + kb * 8);
    bf16x8 bh1 = *(const bf16x8*)(wrow + 32 + kb * 8);
    bf16x8 bl0 = *(const bf16x8*)(wrow + 4096 + kb * 8);
    bf16x8 bl1 = *(const bf16x8*)(wrow + 4096 + 32 + kb * 8);
    __syncthreads();

    // MFMA: wave wid -> output col tile wid. K=64 in 2 steps of 32.
    f32x4 c = {0.f, 0.f, 0.f, 0.f};
    {
        bf16x8 ah0 = *(const bf16x8*)&Ahi[rr][kb * 8];
        bf16x8 am0 = *(const bf16x8*)&Alo[rr][kb * 8];
        c = __builtin_amdgcn_mfma_f32_16x16x32_bf16(ah0, bh0, c, 0, 0, 0);
        c = __builtin_amdgcn_mfma_f32_16x16x32_bf16(ah0, bl0, c, 0, 0, 0);
        c = __builtin_amdgcn_mfma_f32_16x16x32_bf16(am0, bh0, c, 0, 0, 0);
        bf16x8 ah1 = *(const bf16x8*)&Ahi[rr][32 + kb * 8];
        bf16x8 am1 = *(const bf16x8*)&Alo[rr][32 + kb * 8];
        c = __builtin_amdgcn_mfma_f32_16x16x32_bf16(ah1, bh1, c, 0, 0, 0);
        c = __builtin_amdgcn_mfma_f32_16x16x32_bf16(ah1, bl1, c, 0, 0, 0);
        c = __builtin_amdgcn_mfma_f32_16x16x32_bf16(am1, bh1, c, 0, 0, 0);
    }
    // epilogue: D mapping col=l&15, row=(l>>4)*4+reg
    float bv = bias[wid * 16 + rr];
    float4 dq = *(const float4*)&dinv_l[kb * 4];
    const float* dqp = (const float*)&dq;
#pragma unroll
    for (int r = 0; r < 4; ++r) {
        int nd = blockIdx.x * 16 + kb * 4 + r;
        float o = fmaxf(c[r] + bv, 0.f);
        if (!LAST) {
            o *= dqp[r];
            ((unsigned short*)outv)[(size_t)nd * 64 + wid * 16 + rr] = (unsigned short)f2b(o);
        } else {
            ((float*)outv)[(size_t)nd * 64 + wid * 16 + rr] = o;
        }
    }
}

// ---------------------------------------------------------------------------
__global__ void k_pool(const float* __restrict__ h, const int* __restrict__ gstart,
                       float* __restrict__ out) {
    __shared__ float s[4][64];
    int g = blockIdx.x;
    int t = threadIdx.x, lane = t & 63, w = t >> 6;
    int r0 = gstart[g], r1 = gstart[g + 1];
    float acc = 0.f;
    for (int r = r0 + w; r < r1; r += 4) acc += h[(size_t)r * 64 + lane];
    s[w][lane] = acc;
    __syncthreads();
    if (t < 64) {
        float v = s[0][t] + s[1][t] + s[2][t] + s[3][t];
        float c = (float)(r1 - r0);
        out[g * 64 + t] = v / fmaxf(c, 1.f);
    }
}

// ---------------------------------------------------------------------------
static inline size_t al256(size_t x) { return (x + 255) & ~(size_t)255; }

extern "C" void kernel_launch(void* const* d_in, const int* in_sizes, int n_in,
                              void* d_out, int out_size, void* d_ws, size_t ws_size,
                              hipStream_t stream) {
    const float* x     = (const float*)d_in[0];
    const int*   eidx  = (const int*)d_in[1];
    const int*   batch = (const int*)d_in[2];
    const float* W1 = (const float*)d_in[3];  const float* b1 = (const float*)d_in[4];
    const float* W2 = (const float*)d_in[5];  const float* b2 = (const float*)d_in[6];
    const float* W3 = (const float*)d_in[7];  const float* b3 = (const float*)d_in[8];
    const float* W4 = (const float*)d_in[9];  const float* b4 = (const float*)d_in[10];
    float* out = (float*)d_out;
    (void)in_sizes; (void)n_in; (void)out_size; (void)ws_size;

    const int* src = eidx;
    const int* dst = eidx + NE;

    char* p = (char*)d_ws;
    size_t off = 0;
    int*   hrows   = (int*)(p + off);   off = al256(off + sizeof(int) * NBK1 * NB);
    int*   chunkoff= (int*)(p + off);   off = al256(off + sizeof(int) * NBK1 * NB);
    int*   bbase   = (int*)(p + off);   off = al256(off + sizeof(int) * (NB + 1));
    int*   gstart  = (int*)(p + off);   off = al256(off + sizeof(int) * (NG + 1));
    int*   row_off = (int*)(p + off);   off = al256(off + sizeof(int) * (NN + 1));
    float* dinv    = (float*)(p + off); off = al256(off + sizeof(float) * NN);
    unsigned short* wt = (unsigned short*)(p + off); off = al256(off + sizeof(short) * 3 * 8192);
    int*   csr     = (int*)(p + off);   off = al256(off + sizeof(int) * (NE + 16));  // +16 pad for prefetch
    unsigned short* F0 = (unsigned short*)(p + off); off = al256(off + sizeof(short) * (size_t)NN * 64);
    unsigned short* F1 = (unsigned short*)(p + off); off = al256(off + sizeof(short) * (size_t)NN * 64);
    float* H4      = (float*)(p + off); off = al256(off + sizeof(float) * (size_t)NN * 64);
    unsigned*       barray = (unsigned*)H4;        // dead before layer-4 writes H4
    unsigned short* xs     = F1;                   // dead before layer-2 writes F1

    ph0_hist     <<<NBK1, 256, 0, stream>>>(dst, hrows);
    ph_scan      <<<1, NB, 0, stream>>>(hrows, chunkoff, bbase, row_off);
    ph1_bucketize<<<NBK1, 256, 0, stream>>>(src, dst, chunkoff, barray);
    ph2_build    <<<NB, 256, 0, stream>>>(barray, bbase, row_off, dinv, csr);
    k_prep       <<<3 + NBND_BLK + NPAD_BLK, 256, 0, stream>>>(W2, W3, W4, wt, x, dinv, xs, batch, gstart);

    fused1        <<<(NN + 63) / 64, 256, 0, stream>>>(xs, row_off, csr, dinv, W1, b1, (unsigned*)F0);
    fused64<false><<<NN / 16, 256, 0, stream>>>(F0, row_off, csr, dinv, wt,        b2, F1);
    fused64<false><<<NN / 16, 256, 0, stream>>>(F1, row_off, csr, dinv, wt + 8192, b3, F0);
    fused64<true> <<<NN / 16, 256, 0, stream>>>(F0, row_off, csr, dinv, wt + 16384,b4, H4);

    k_pool  <<<NG, 256, 0, stream>>>(H4, gstart, out);
}

// Round 10
// 180.562 us; speedup vs baseline: 1.1532x; 1.1532x over previous
//
#include <hip/hip_runtime.h>
#include <hip/hip_bf16.h>

#define NN 100000
#define NE 1200000
#define NG 256
#define NB 256          // dst buckets
#define BSZ 391         // nodes per bucket (ceil(NN/NB))
#define NBK1 128        // ph0/ph1 blocks
#define ECH 9376        // edges per block (128*9376 >= NE)
#define MAXB 6144       // max edges per bucket (mean 4692)
#define NBND_BLK 391    // ceil(NN/256) for bounds
#define NPAD_BLK 6250   // NN*16/256

typedef __attribute__((ext_vector_type(8))) short bf16x8;
typedef __attribute__((ext_vector_type(4))) float f32x4;

// bf16 helpers (RNE)
__device__ __forceinline__ unsigned f2b(float f) {
    unsigned b = __float_as_uint(f);
    return (b + 0x7FFFu + ((b >> 16) & 1u)) >> 16;
}
__device__ __forceinline__ float b2f(unsigned short u) {
    return __uint_as_float((unsigned)u << 16);
}
__device__ __forceinline__ float4 b2f4(ushort4 u) {
    return make_float4(b2f(u.x), b2f(u.y), b2f(u.z), b2f(u.w));
}
// accumulate 8 bf16 channels (uint4) into float[8]
__device__ __forceinline__ void add_u4(float* a, uint4 v) {
    const unsigned* u = (const unsigned*)&v;
#pragma unroll
    for (int i = 0; i < 4; ++i) {
        a[2*i]   += __uint_as_float(u[i] << 16);
        a[2*i+1] += __uint_as_float(u[i] & 0xFFFF0000u);
    }
}

// ---------------------------------------------------------------------------
// Phase 0: per-block bucket histogram rows (no global atomics, no memset)
__global__ void ph0_hist(const int* __restrict__ dst, int* __restrict__ hrows) {
    __shared__ int h[NB];
    const int t = threadIdx.x;
    h[t] = 0;
    __syncthreads();
    const int e0 = blockIdx.x * ECH;
    const int cnt = min(ECH, NE - e0);
    for (int i = t; i < cnt; i += 256)
        atomicAdd(&h[dst[e0 + i] / BSZ], 1);
    __syncthreads();
    hrows[blockIdx.x * NB + t] = h[t];
}

// Phase 0b-A: per-bucket parallel scan over the 128 block counts
__global__ void ph_scanA(const int* __restrict__ hrows, int* __restrict__ chunkoff,
                         int* __restrict__ btot) {
    __shared__ int s[NBK1];
    const int b = threadIdx.x;      // block index 0..127
    const int t = blockIdx.x;       // bucket
    int v = hrows[b * NB + t];
    s[b] = v;
    __syncthreads();
    for (int off = 1; off < NBK1; off <<= 1) {
        int u = (b >= off) ? s[b - off] : 0;
        __syncthreads();
        s[b] += u;
        __syncthreads();
    }
    chunkoff[b * NB + t] = s[b] - v;            // exclusive, bucket-local
    if (b == NBK1 - 1) btot[t] = s[b];
}

// Phase 0b-B: scan bucket totals -> bbase
__global__ void ph_scanB(const int* __restrict__ btot, int* __restrict__ bbase,
                         int* __restrict__ row_off) {
    __shared__ int s[NB];
    const int t = threadIdx.x;
    int v = btot[t];
    s[t] = v;
    __syncthreads();
    for (int off = 1; off < NB; off <<= 1) {
        int u = (t >= off) ? s[t - off] : 0;
        __syncthreads();
        s[t] += u;
        __syncthreads();
    }
    bbase[t] = s[t] - v;
    if (t == NB - 1) { bbase[NB] = NE; row_off[NN] = NE; }
}

// Phase 1: single-pass bucketize, LDS cursors only (no global atomics)
__global__ void ph1_bucketize(const int* __restrict__ src, const int* __restrict__ dst,
                              const int* __restrict__ chunkoff, const int* __restrict__ bbase,
                              unsigned* __restrict__ barray) {
    __shared__ int lbase[NB];
    __shared__ int lcur[NB];
    const int t = threadIdx.x;
    lbase[t] = bbase[t] + chunkoff[blockIdx.x * NB + t];
    lcur[t] = 0;
    __syncthreads();
    const int e0 = blockIdx.x * ECH;
    const int cnt = min(ECH, NE - e0);
    for (int i = t; i < cnt; i += 256) {
        int d = dst[e0 + i], s = src[e0 + i];
        int b = d / BSZ;
        int pos = lbase[b] + atomicAdd(&lcur[b], 1);
        barray[pos] = ((unsigned)(d - b * BSZ) << 17) | (unsigned)s;
    }
}

// Phase 2: per-bucket CSR build, all global writes coalesced
__global__ void ph2_build(const unsigned* __restrict__ barray, const int* __restrict__ bbase,
                          int* __restrict__ row_off, float* __restrict__ dinv,
                          int* __restrict__ csr) {
    __shared__ unsigned estage[MAXB];
    __shared__ int lcsr[MAXB];
    __shared__ int s[512];
    __shared__ int cur[BSZ];
    const int t = threadIdx.x;
    const int b = blockIdx.x;
    const int ebase = bbase[b];
    const int cnt = bbase[b + 1] - ebase;
    const int nbase = b * BSZ;
    const int nnodes = min(BSZ, NN - nbase);
    s[t] = 0; s[t + 256] = 0;
    __syncthreads();
    for (int i = t; i < cnt; i += 256) {
        unsigned e = barray[ebase + i];
        estage[i] = e;
        atomicAdd(&s[e >> 17], 1);
    }
    __syncthreads();
    for (int off = 1; off < 512; off <<= 1) {
        int v1 = (t >= off) ? s[t - off] : 0;
        int v2 = s[t + 256 - off];
        __syncthreads();
        s[t] += v1; s[t + 256] += v2;
        __syncthreads();
    }
    for (int l = t; l < nnodes; l += 256) {
        int incl = s[l];
        int excl = l ? s[l - 1] : 0;
        row_off[nbase + l] = ebase + excl;
        dinv[nbase + l] = rsqrtf((float)(incl - excl) + 1.0f);
        cur[l] = excl;
    }
    __syncthreads();
    for (int i = t; i < cnt; i += 256) {
        unsigned e = estage[i];
        int pos = atomicAdd(&cur[e >> 17], 1);
        lcsr[pos] = (int)(e & 0x1FFFFu);
    }
    __syncthreads();
    for (int i = t; i < cnt; i += 256)
        csr[ebase + i] = lcsr[i];
}

// ---------------------------------------------------------------------------
// Combined prep: blocks [0,3) W-split, [3,394) pool bounds, [394,...) x pad
__global__ void k_prep(const float* __restrict__ W2, const float* __restrict__ W3,
                       const float* __restrict__ W4, unsigned short* __restrict__ wt,
                       const float* __restrict__ x, const float* __restrict__ dinv,
                       unsigned short* __restrict__ xs,
                       const int* __restrict__ batch, int* __restrict__ gstart) {
    const int blk = blockIdx.x;
    const int t = threadIdx.x;
    if (blk < 3) {
        // W -> transposed, hi/lo-split bf16: per layer [hi 64x64][lo 64x64]
        const float* W = (blk == 0) ? W2 : (blk == 1) ? W3 : W4;
        unsigned short* o = wt + blk * 8192;
        const int n = t >> 2;
        const int j0 = (t & 3) * 16;
#pragma unroll
        for (int j = 0; j < 16; ++j) {
            float wv = W[(j0 + j) * 64 + n];
            unsigned short h = (unsigned short)f2b(wv);
            o[n * 64 + j0 + j] = h;
            o[4096 + n * 64 + j0 + j] = (unsigned short)f2b(wv - b2f(h));
        }
    } else if (blk < 3 + NBND_BLK) {
        int i = (blk - 3) * 256 + t;
        if (i >= NN) return;
        int b = batch[i];
        if (i == 0) {
            for (int g = 0; g <= b; ++g) gstart[g] = 0;
        } else {
            int bp = batch[i - 1];
            for (int g = bp + 1; g <= b; ++g) gstart[g] = i;
        }
        if (i == NN - 1) {
            for (int g = b + 1; g <= NG; ++g) gstart[g] = NN;
        }
    } else {
        int i = (blk - 3 - NBND_BLK) * 256 + t;
        if (i < NN * 16) {
            int n = i >> 4, k = i & 15;
            float v = (k < 15) ? dinv[n] * x[n * 15 + k] : 0.f;
            xs[i] = (unsigned short)f2b(v);
        }
    }
}

// ---------------------------------------------------------------------------
// Layer 1: 16-d bf16 gather -> 16x64 matmul (VALU) -> bf16 out. 64 nodes/block.
__global__ void fused1(const unsigned short* __restrict__ xs, const int* __restrict__ row_off,
                       const int* __restrict__ csr, const float* __restrict__ dinv,
                       const float* __restrict__ W, const float* __restrict__ bias,
                       unsigned* __restrict__ out) {
    __shared__ float4 Wl[16][16];
    __shared__ float  al[64][20];
    const int t = threadIdx.x;
    if (t < 240) Wl[t >> 4][t & 15] = ((const float4*)W)[t];
    if (t < 16) Wl[15][t] = make_float4(0,0,0,0);
    const int nl = t >> 2, c4 = t & 3;
    const int node = blockIdx.x * 64 + nl;
    float4 acc = make_float4(0,0,0,0);
    float dv = 0.f;
    if (node < NN) {
        const ushort4* base = (const ushort4*)xs;
        acc = b2f4(base[(size_t)node * 4 + c4]);
        int p = row_off[node], e = row_off[node + 1];
        for (; p + 3 < e; p += 4) {
            int s0 = csr[p], s1 = csr[p+1], s2 = csr[p+2], s3 = csr[p+3];
            float4 a = b2f4(base[(size_t)s0 * 4 + c4]);
            float4 b = b2f4(base[(size_t)s1 * 4 + c4]);
            float4 c = b2f4(base[(size_t)s2 * 4 + c4]);
            float4 d = b2f4(base[(size_t)s3 * 4 + c4]);
            acc.x += (a.x + b.x) + (c.x + d.x);
            acc.y += (a.y + b.y) + (c.y + d.y);
            acc.z += (a.z + b.z) + (c.z + d.z);
            acc.w += (a.w + b.w) + (c.w + d.w);
        }
        for (; p < e; ++p) {
            float4 a = b2f4(base[(size_t)csr[p] * 4 + c4]);
            acc.x += a.x; acc.y += a.y; acc.z += a.z; acc.w += a.w;
        }
        dv = dinv[node];
        acc.x *= dv; acc.y *= dv; acc.z *= dv; acc.w *= dv;
    }
    ((float4*)&al[nl][0])[c4] = acc;
    __syncthreads();
    if (node >= NN) return;
    float4 o0 = ((const float4*)bias)[c4 * 4 + 0];
    float4 o1 = ((const float4*)bias)[c4 * 4 + 1];
    float4 o2 = ((const float4*)bias)[c4 * 4 + 2];
    float4 o3 = ((const float4*)bias)[c4 * 4 + 3];
#pragma unroll
    for (int k = 0; k < 16; ++k) {
        float a = al[nl][k];
        float4 w0 = Wl[k][c4 * 4 + 0];
        float4 w1 = Wl[k][c4 * 4 + 1];
        float4 w2 = Wl[k][c4 * 4 + 2];
        float4 w3 = Wl[k][c4 * 4 + 3];
        o0.x = fmaf(a, w0.x, o0.x); o0.y = fmaf(a, w0.y, o0.y); o0.z = fmaf(a, w0.z, o0.z); o0.w = fmaf(a, w0.w, o0.w);
        o1.x = fmaf(a, w1.x, o1.x); o1.y = fmaf(a, w1.y, o1.y); o1.z = fmaf(a, w1.z, o1.z); o1.w = fmaf(a, w1.w, o1.w);
        o2.x = fmaf(a, w2.x, o2.x); o2.y = fmaf(a, w2.y, o2.y); o2.z = fmaf(a, w2.z, o2.z); o2.w = fmaf(a, w2.w, o2.w);
        o3.x = fmaf(a, w3.x, o3.x); o3.y = fmaf(a, w3.y, o3.y); o3.z = fmaf(a, w3.z, o3.z); o3.w = fmaf(a, w3.w, o3.w);
    }
    float dv2 = dv;
    o0.x = fmaxf(o0.x, 0.f) * dv2; o0.y = fmaxf(o0.y, 0.f) * dv2; o0.z = fmaxf(o0.z, 0.f) * dv2; o0.w = fmaxf(o0.w, 0.f) * dv2;
    o1.x = fmaxf(o1.x, 0.f) * dv2; o1.y = fmaxf(o1.y, 0.f) * dv2; o1.z = fmaxf(o1.z, 0.f) * dv2; o1.w = fmaxf(o1.w, 0.f) * dv2;
    o2.x = fmaxf(o2.x, 0.f) * dv2; o2.y = fmaxf(o2.y, 0.f) * dv2; o2.z = fmaxf(o2.z, 0.f) * dv2; o2.w = fmaxf(o2.w, 0.f) * dv2;
    o3.x = fmaxf(o3.x, 0.f) * dv2; o3.y = fmaxf(o3.y, 0.f) * dv2; o3.z = fmaxf(o3.z, 0.f) * dv2; o3.w = fmaxf(o3.w, 0.f) * dv2;
    uint4 lo, hi;
    lo.x = f2b(o0.x) | (f2b(o0.y) << 16);
    lo.y = f2b(o0.z) | (f2b(o0.w) << 16);
    lo.z = f2b(o1.x) | (f2b(o1.y) << 16);
    lo.w = f2b(o1.z) | (f2b(o1.w) << 16);
    hi.x = f2b(o2.x) | (f2b(o2.y) << 16);
    hi.y = f2b(o2.z) | (f2b(o2.w) << 16);
    hi.z = f2b(o3.x) | (f2b(o3.y) << 16);
    hi.w = f2b(o3.z) | (f2b(o3.w) << 16);
    uint4* ob = (uint4*)out + (size_t)node * 8 + c4 * 2;
    ob[0] = lo; ob[1] = hi;
}

// ---------------------------------------------------------------------------
// Layers 2..4: bf16 gather (8 lanes x 16B/row, 2 sub-groups/node, unroll-8,
// shfl_xor combine) -> MFMA 16x16x32 hi/lo split. B staged via LDS (round-8
// proven form).
template <bool LAST>
__global__ __launch_bounds__(256) void fused64(const unsigned short* __restrict__ g,
                        const int* __restrict__ row_off, const int* __restrict__ csr,
                        const float* __restrict__ dinv, const unsigned short* __restrict__ wt,
                        const float* __restrict__ bias, void* __restrict__ outv) {
    __shared__ alignas(16) unsigned short Ahi[16][72];
    __shared__ alignas(16) unsigned short Alo[16][72];
    __shared__ alignas(16) unsigned short Bhi[64][72];
    __shared__ alignas(16) unsigned short Blo[64][72];
    __shared__ alignas(16) float dinv_l[16];
    const int t = threadIdx.x;

    // stage pre-split W: 1024 coalesced uint4 -> padded LDS rows
    {
        const uint4* srcv = (const uint4*)wt;
#pragma unroll
        for (int i = 0; i < 4; ++i) {
            int idx = t + i * 256;
            uint4 v = srcv[idx];
            int sel = idx >> 9, r = idx & 511;
            int n = r >> 3, kc = r & 7;
            unsigned short* dstp = sel ? &Blo[n][kc * 8] : &Bhi[n][kc * 8];
            *(uint4*)dstp = v;
        }
    }

    // gather: node = t>>4; sub-group s8 = (t>>3)&1 takes half the edges;
    // lane q = t&7 covers channels q*8..q*8+7 (one uint4 = 16 B of the row).
    const int nl = t >> 4;
    const int s8 = (t >> 3) & 1;
    const int q  = t & 7;
    const int node = blockIdx.x * 16 + nl;
    float acc[8] = {0,0,0,0,0,0,0,0};
    const float dv = dinv[node];
    {
        const uint4* fbase = (const uint4*)g;        // row = 8 x uint4 (128 B)
        const int r0 = row_off[node], r1 = row_off[node + 1];
        const int half = (r1 - r0 + 1) >> 1;
        int p = r0 + s8 * half;
        const int e = s8 ? r1 : (r0 + half);
        if (s8 == 0) add_u4(acc, fbase[(size_t)node * 8 + q]);   // self-loop
        int i0 = csr[p],   i1 = csr[p+1], i2 = csr[p+2], i3 = csr[p+3];
        int i4 = csr[p+4], i5 = csr[p+5], i6 = csr[p+6], i7 = csr[p+7];
        while (p < e) {
            const int rem = e - p;
            uint4 v0, v1, v2, v3, v4, v5, v6, v7;
            v0 = fbase[(size_t)i0 * 8 + q];
            if (rem > 1) v1 = fbase[(size_t)i1 * 8 + q];
            if (rem > 2) v2 = fbase[(size_t)i2 * 8 + q];
            if (rem > 3) v3 = fbase[(size_t)i3 * 8 + q];
            if (rem > 4) v4 = fbase[(size_t)i4 * 8 + q];
            if (rem > 5) v5 = fbase[(size_t)i5 * 8 + q];
            if (rem > 6) v6 = fbase[(size_t)i6 * 8 + q];
            if (rem > 7) v7 = fbase[(size_t)i7 * 8 + q];
            p += 8;
            i0 = csr[p];   i1 = csr[p+1]; i2 = csr[p+2]; i3 = csr[p+3];
            i4 = csr[p+4]; i5 = csr[p+5]; i6 = csr[p+6]; i7 = csr[p+7];
            add_u4(acc, v0);
            if (rem > 1) add_u4(acc, v1);
            if (rem > 2) add_u4(acc, v2);
            if (rem > 3) add_u4(acc, v3);
            if (rem > 4) add_u4(acc, v4);
            if (rem > 5) add_u4(acc, v5);
            if (rem > 6) add_u4(acc, v6);
            if (rem > 7) add_u4(acc, v7);
        }
    }
    // combine the two sub-groups in-register (lanes differ in bit 3)
#pragma unroll
    for (int i = 0; i < 8; ++i) acc[i] += __shfl_xor(acc[i], 8, 64);
    if (s8 == 0) {
        uint4 uh, ul;
        unsigned* uhp = (unsigned*)&uh;
        unsigned* ulp = (unsigned*)&ul;
#pragma unroll
        for (int i = 0; i < 4; ++i) {
            float va = acc[2*i] * dv;
            float vb = acc[2*i+1] * dv;
            unsigned ha = f2b(va), hb = f2b(vb);
            unsigned la = f2b(va - b2f((unsigned short)ha));
            unsigned lb = f2b(vb - b2f((unsigned short)hb));
            uhp[i] = ha | (hb << 16);
            ulp[i] = la | (lb << 16);
        }
        *(uint4*)&Ahi[nl][q * 8] = uh;
        *(uint4*)&Alo[nl][q * 8] = ul;
        if (q == 0) dinv_l[nl] = dv;
    }
    __syncthreads();

    // MFMA: wave wid -> output col tile wid. K=64 in 2 steps of 32.
    const int wid = t >> 6;
    const int l = t & 63;
    const int rr = l & 15;
    const int kb = l >> 4;
    f32x4 c = {0.f, 0.f, 0.f, 0.f};
#pragma unroll
    for (int ks = 0; ks < 2; ++ks) {
        bf16x8 ah = *(const bf16x8*)&Ahi[rr][ks * 32 + kb * 8];
        bf16x8 am = *(const bf16x8*)&Alo[rr][ks * 32 + kb * 8];
        bf16x8 bh = *(const bf16x8*)&Bhi[wid * 16 + rr][ks * 32 + kb * 8];
        bf16x8 bl = *(const bf16x8*)&Blo[wid * 16 + rr][ks * 32 + kb * 8];
        c = __builtin_amdgcn_mfma_f32_16x16x32_bf16(ah, bh, c, 0, 0, 0);
        c = __builtin_amdgcn_mfma_f32_16x16x32_bf16(ah, bl, c, 0, 0, 0);
        c = __builtin_amdgcn_mfma_f32_16x16x32_bf16(am, bh, c, 0, 0, 0);
    }
    // epilogue: D mapping col=l&15, row=(l>>4)*4+reg
    float bv = bias[wid * 16 + rr];
    float4 dq = *(const float4*)&dinv_l[kb * 4];
    const float* dqp = (const float*)&dq;
#pragma unroll
    for (int r = 0; r < 4; ++r) {
        int nd = blockIdx.x * 16 + kb * 4 + r;
        float o = fmaxf(c[r] + bv, 0.f);
        if (!LAST) {
            o *= dqp[r];
            ((unsigned short*)outv)[(size_t)nd * 64 + wid * 16 + rr] = (unsigned short)f2b(o);
        } else {
            ((float*)outv)[(size_t)nd * 64 + wid * 16 + rr] = o;
        }
    }
}

// ---------------------------------------------------------------------------
__global__ void k_pool(const float* __restrict__ h, const int* __restrict__ gstart,
                       float* __restrict__ out) {
    __shared__ float s[4][64];
    int g = blockIdx.x;
    int t = threadIdx.x, lane = t & 63, w = t >> 6;
    int r0 = gstart[g], r1 = gstart[g + 1];
    float acc = 0.f;
    for (int r = r0 + w; r < r1; r += 4) acc += h[(size_t)r * 64 + lane];
    s[w][lane] = acc;
    __syncthreads();
    if (t < 64) {
        float v = s[0][t] + s[1][t] + s[2][t] + s[3][t];
        float c = (float)(r1 - r0);
        out[g * 64 + t] = v / fmaxf(c, 1.f);
    }
}

// ---------------------------------------------------------------------------
static inline size_t al256(size_t x) { return (x + 255) & ~(size_t)255; }

extern "C" void kernel_launch(void* const* d_in, const int* in_sizes, int n_in,
                              void* d_out, int out_size, void* d_ws, size_t ws_size,
                              hipStream_t stream) {
    const float* x     = (const float*)d_in[0];
    const int*   eidx  = (const int*)d_in[1];
    const int*   batch = (const int*)d_in[2];
    const float* W1 = (const float*)d_in[3];  const float* b1 = (const float*)d_in[4];
    const float* W2 = (const float*)d_in[5];  const float* b2 = (const float*)d_in[6];
    const float* W3 = (const float*)d_in[7];  const float* b3 = (const float*)d_in[8];
    const float* W4 = (const float*)d_in[9];  const float* b4 = (const float*)d_in[10];
    float* out = (float*)d_out;
    (void)in_sizes; (void)n_in; (void)out_size; (void)ws_size;

    const int* src = eidx;
    const int* dst = eidx + NE;

    char* p = (char*)d_ws;
    size_t off = 0;
    int*   hrows   = (int*)(p + off);   off = al256(off + sizeof(int) * NBK1 * NB);
    int*   chunkoff= (int*)(p + off);   off = al256(off + sizeof(int) * NBK1 * NB);
    int*   btot    = (int*)(p + off);   off = al256(off + sizeof(int) * NB);
    int*   bbase   = (int*)(p + off);   off = al256(off + sizeof(int) * (NB + 1));
    int*   gstart  = (int*)(p + off);   off = al256(off + sizeof(int) * (NG + 1));
    int*   row_off = (int*)(p + off);   off = al256(off + sizeof(int) * (NN + 1));
    float* dinv    = (float*)(p + off); off = al256(off + sizeof(float) * NN);
    unsigned short* wt = (unsigned short*)(p + off); off = al256(off + sizeof(short) * 3 * 8192);
    int*   csr     = (int*)(p + off);   off = al256(off + sizeof(int) * (NE + 16));  // +16 pad for prefetch
    unsigned short* F0 = (unsigned short*)(p + off); off = al256(off + sizeof(short) * (size_t)NN * 64);
    unsigned short* F1 = (unsigned short*)(p + off); off = al256(off + sizeof(short) * (size_t)NN * 64);
    float* H4      = (float*)(p + off); off = al256(off + sizeof(float) * (size_t)NN * 64);
    unsigned*       barray = (unsigned*)H4;        // dead before layer-4 writes H4
    unsigned short* xs     = F1;                   // dead before layer-2 writes F1

    ph0_hist     <<<NBK1, 256, 0, stream>>>(dst, hrows);
    ph_scanA     <<<NB, NBK1, 0, stream>>>(hrows, chunkoff, btot);
    ph_scanB     <<<1, NB, 0, stream>>>(btot, bbase, row_off);
    ph1_bucketize<<<NBK1, 256, 0, stream>>>(src, dst, chunkoff, bbase, barray);
    ph2_build    <<<NB, 256, 0, stream>>>(barray, bbase, row_off, dinv, csr);
    k_prep       <<<3 + NBND_BLK + NPAD_BLK, 256, 0, stream>>>(W2, W3, W4, wt, x, dinv, xs, batch, gstart);

    fused1        <<<(NN + 63) / 64, 256, 0, stream>>>(xs, row_off, csr, dinv, W1, b1, (unsigned*)F0);
    fused64<false><<<NN / 16, 256, 0, stream>>>(F0, row_off, csr, dinv, wt,        b2, F1);
    fused64<false><<<NN / 16, 256, 0, stream>>>(F1, row_off, csr, dinv, wt + 8192, b3, F0);
    fused64<true> <<<NN / 16, 256, 0, stream>>>(F0, row_off, csr, dinv, wt + 16384,b4, H4);

    k_pool  <<<NG, 256, 0, stream>>>(H4, gstart, out);
}